// Round 11
// baseline (3557.120 us; speedup 1.0000x reference)
//
#include <hip/hip_runtime.h>
#include <stdint.h>

// VanillaRNN: B=128, T=512, I=128, H=2048, O=10
// R11: FLAG-FREE handoff. tanh(h) in [-1,1] => f16 bit14 is always 0; producers
//   tag every stored f16 with step parity in bit14. Consumers load h directly
//   and retry until all tags match expected parity (then mask for odd steps).
//   - removes flag store + flag poll (2 RTTs) and the producer store-drain
//     barrier (stores fire-and-forget; red[] parity-double-buffered).
//   - 3-buffer rotation => stale data is s_{t-3}, opposite parity, rejected.
//   - prep_init re-clears buffers each launch (replay-safe).
//   h stores: sc0 sc1 write-through (proven). h loads: sc1.

#define B_   128
#define T_   512
#define I_   128
#define H_   2048
#define O_   10
#define KK   2176
#define NWG  256
#define NTHR 512
#define TAG2 0x40004000u
#define MSK2 0xBFFFBFFFu

typedef __attribute__((ext_vector_type(8))) _Float16 f16x8;
typedef __attribute__((ext_vector_type(4))) float    f32x4;
typedef __attribute__((ext_vector_type(4))) int      i32x4;

__device__ __forceinline__ float f16_to_f(unsigned short u) {
    return (float)__builtin_bit_cast(_Float16, u);
}
__device__ __forceinline__ unsigned short f_to_f16(float f) {
    return __builtin_bit_cast(unsigned short, (_Float16)f);
}

// system-scope write-through stores (proven visibility)
__device__ __forceinline__ void st16cc(unsigned short* p, unsigned short v) {
    asm volatile("global_store_short %0, %1, off sc0 sc1"
                 :: "v"((uint64_t)(uintptr_t)p), "v"((uint32_t)v) : "memory");
}
__device__ __forceinline__ void st32cc(uint32_t* p, uint32_t v) {
    asm volatile("global_store_dword %0, %1, off sc0 sc1"
                 :: "v"((uint64_t)(uintptr_t)p), "v"(v) : "memory");
}

#define MFMA16(a, b, c) __builtin_amdgcn_mfma_f32_16x16x32_f16((a), (b), (c), 0, 0, 0)

// Clear the 3 h buffers with tag-invalid patterns (replay safety):
// buf0/buf1 first expected with parity1 -> clear tag0; buf2 first expected parity0 -> clear tag1.
__global__ void prep_init(unsigned short* h0, unsigned short* h1, unsigned short* h2) {
    const int i = blockIdx.x * blockDim.x + threadIdx.x;   // 0..131071 (dwords)
    st32cc((uint32_t*)h0 + i, 0u);
    st32cc((uint32_t*)h1 + i, 0u);
    st32cc((uint32_t*)h2 + i, TAG2);
}

// Transpose + f16 convert: Wt[n][k]; k<2048 -> W_hh, k>=2048 -> W_hx.
__global__ void prep_weights(const float* __restrict__ Whh, const float* __restrict__ Whx,
                             unsigned short* __restrict__ Wt) {
    __shared__ float tile[32][33];
    const int kt = blockIdx.x;
    const int nt = blockIdx.y;
    const int tx = threadIdx.x & 31;
    const int ty = threadIdx.x >> 5;
#pragma unroll
    for (int r = ty; r < 32; r += 8) {
        const int k = kt * 32 + r;
        const int n = nt * 32 + tx;
        tile[r][tx] = (k < H_) ? Whh[(size_t)k * H_ + n] : Whx[(size_t)(k - H_) * H_ + n];
    }
    __syncthreads();
#pragma unroll
    for (int r = ty; r < 32; r += 8) {
        const int n = nt * 32 + r;
        const int k = kt * 32 + tx;
        Wt[(size_t)n * KK + k] = f_to_f16(tile[tx][r]);
    }
}

__global__ __launch_bounds__(NTHR, 2) void rnn_scan(
    const float* __restrict__ x,              // [B][T][I] f32
    const unsigned short* __restrict__ Wt,    // [H][KK] f16
    const float* __restrict__ b_h,
    const float* __restrict__ W_ph,           // [H][O]
    const float* __restrict__ b_o,
    unsigned short* __restrict__ h0,          // s_t with t%3==0
    unsigned short* __restrict__ h1,          // t%3==1
    unsigned short* __restrict__ h2,          // t%3==2
    float* __restrict__ out)                  // [B][O]
{
    const int tid  = threadIdx.x;
    const int wg   = blockIdx.x;
    const int w    = tid >> 6;        // wave 0..7 = k-eighth
    const int lane = tid & 63;
    const int l15  = lane & 15;
    const int l4   = lane >> 4;
    const int rb   = wg >> 5;         // row-group 0..7 (rows rb*16..+16)
    const int cb   = wg & 31;         // col block 0..31
    const int r0   = rb * 16;
    const int c0   = cb * 64;
    const int arow = r0 + l15;

    __shared__ f32x4 red[2][8][4][64];       // parity-double-buffered (64 KB)
    __shared__ float epi[128];
    __shared__ float lgt[16];

    // ---- W panel into registers (f16, const over t) ----
    i32x4 wh[4][8];
    i32x4 wx[4];
#pragma unroll
    for (int n = 0; n < 4; ++n) {
        const size_t colbase = (size_t)(c0 + n * 16 + l15) * KK;
#pragma unroll
        for (int j = 0; j < 8; ++j)
            wh[n][j] = *(const i32x4*)(Wt + colbase + (size_t)(w * 256 + j * 32 + l4 * 8));
        if (w >= 4)
            wx[n] = *(const i32x4*)(Wt + colbase + (size_t)(2048 + (w - 4) * 32 + l4 * 8));
    }

    // reducer constants (tid < 256)
    const int rn    = tid >> 6;
    const int rL    = tid & 63;
    const int rcol  = c0 + rn * 16 + (rL & 15);
    const int rrow0 = r0 + (rL >> 4) * 4;
    const float rbias = b_h[rcol];

    // 3-buffer rotation: iter t reads cur (s_t), writes nxt (s_{t+1})
    unsigned short* cur = h0;
    unsigned short* nxt = h1;
    unsigned short* old = h2;

    for (int t = 0; t < T_; ++t) {
        const int par = t & 1;                 // expected tag parity of s_t

        f32x4 acc[4];
#pragma unroll
        for (int n = 0; n < 4; ++n) acc[n] = f32x4{0.f, 0.f, 0.f, 0.f};

        i32x4 hb[8];
        const uint64_t base64 = (uint64_t)(uintptr_t)(cur + (size_t)arow * H_ + (size_t)(w * 256 + l4 * 8));

#define ISSALL() do { \
    asm volatile("global_load_dwordx4 %0, %1, off offset:0 sc1"   : "=v"(hb[0]) : "v"(base64) : "memory"); \
    asm volatile("global_load_dwordx4 %0, %1, off offset:64 sc1"  : "=v"(hb[1]) : "v"(base64) : "memory"); \
    asm volatile("global_load_dwordx4 %0, %1, off offset:128 sc1" : "=v"(hb[2]) : "v"(base64) : "memory"); \
    asm volatile("global_load_dwordx4 %0, %1, off offset:192 sc1" : "=v"(hb[3]) : "v"(base64) : "memory"); \
    asm volatile("global_load_dwordx4 %0, %1, off offset:256 sc1" : "=v"(hb[4]) : "v"(base64) : "memory"); \
    asm volatile("global_load_dwordx4 %0, %1, off offset:320 sc1" : "=v"(hb[5]) : "v"(base64) : "memory"); \
    asm volatile("global_load_dwordx4 %0, %1, off offset:384 sc1" : "=v"(hb[6]) : "v"(base64) : "memory"); \
    asm volatile("global_load_dwordx4 %0, %1, off offset:448 sc1" : "=v"(hb[7]) : "v"(base64) : "memory"); \
    } while (0)
#define WAITV0() do { \
    asm volatile("s_waitcnt vmcnt(0)" ::: "memory"); \
    __builtin_amdgcn_sched_barrier(0); } while (0)

        // issue first h-load attempt ASAP (overlaps x block below)
        if (t > 0) ISSALL();

        // ---- x contribution (waves 4..7) ----
        if (w >= 4) {
            const float* xp = x + ((size_t)arow * T_ + t) * I_ + (size_t)((w - 4) * 32 + l4 * 8);
            const f32x4 xa = *(const f32x4*)xp;
            const f32x4 xb = *(const f32x4*)(xp + 4);
            f16x8 xv;
#pragma unroll
            for (int jj = 0; jj < 8; ++jj)
                xv[jj] = (_Float16)((jj < 4) ? xa[jj] : xb[jj - 4]);
#pragma unroll
            for (int n = 0; n < 4; ++n)
                acc[n] = MFMA16(xv, __builtin_bit_cast(f16x8, wx[n]), acc[n]);
        }

        if (t > 0) {
            // ---- retry until every f16 carries tag parity == par ----
            for (;;) {
                WAITV0();
                uint32_t a;
                if (par) {
                    a = 0xFFFFFFFFu;
#pragma unroll
                    for (int j = 0; j < 8; ++j) {
                        a &= (uint32_t)hb[j][0]; a &= (uint32_t)hb[j][1];
                        a &= (uint32_t)hb[j][2]; a &= (uint32_t)hb[j][3];
                    }
                } else {
                    a = 0u;
#pragma unroll
                    for (int j = 0; j < 8; ++j) {
                        a |= (uint32_t)hb[j][0]; a |= (uint32_t)hb[j][1];
                        a |= (uint32_t)hb[j][2]; a |= (uint32_t)hb[j][3];
                    }
                }
                const int ok = par ? ((a & TAG2) == TAG2) : ((a & TAG2) == 0u);
                if (__all(ok)) break;
                ISSALL();
            }
            // strip tags (odd parity only; even parity bit14 is already 0)
            if (par) {
#pragma unroll
                for (int j = 0; j < 8; ++j) {
                    hb[j][0] = (int)((uint32_t)hb[j][0] & MSK2);
                    hb[j][1] = (int)((uint32_t)hb[j][1] & MSK2);
                    hb[j][2] = (int)((uint32_t)hb[j][2] & MSK2);
                    hb[j][3] = (int)((uint32_t)hb[j][3] & MSK2);
                }
            }
            // ---- h MFMAs ----
#pragma unroll
            for (int j = 0; j < 8; ++j) {
                const f16x8 AH = __builtin_bit_cast(f16x8, hb[j]);
                acc[0] = MFMA16(AH, __builtin_bit_cast(f16x8, wh[0][j]), acc[0]);
                acc[1] = MFMA16(AH, __builtin_bit_cast(f16x8, wh[1][j]), acc[1]);
                acc[2] = MFMA16(AH, __builtin_bit_cast(f16x8, wh[2][j]), acc[2]);
                acc[3] = MFMA16(AH, __builtin_bit_cast(f16x8, wh[3][j]), acc[3]);
            }
        }
#undef ISSALL

        // ---- cross-wave k-reduce (parity-buffered; ONE barrier per step) ----
#pragma unroll
        for (int n = 0; n < 4; ++n) red[par][w][n][lane] = acc[n];
        __syncthreads();

        if (tid < 256) {
            f32x4 v = red[par][0][rn][rL];
#pragma unroll
            for (int p = 1; p < 8; ++p) v += red[par][p][rn][rL];
            const unsigned int tagbit = (unsigned int)((t + 1) & 1) << 14;
#pragma unroll
            for (int r = 0; r < 4; ++r) {
                const unsigned short hv = f_to_f16(tanhf(v[r] + rbias)) | tagbit;
                st16cc(nxt + (size_t)(rrow0 + r) * H_ + rcol, hv);   // fire-and-forget
            }
        }

        // rotate buffers: (cur,nxt,old) <- (nxt, old, cur)
        unsigned short* tmp = cur;
        cur = nxt; nxt = old; old = tmp;
    }

    // ---- epilogue: row r0+cb handled by OWNER group rb (cb<16) ----
    // h_T = s_512 lives in buf[512%3] = h2, tag parity 0 (untagged values).
    if (cb < 16) {
        const int b = r0 + cb;
        const uint64_t hbase = (uint64_t)(uintptr_t)(h2 + (size_t)b * H_ + (size_t)tid * 4);
        uint64_t hh;
        for (;;) {
            asm volatile("global_load_dwordx2 %0, %1, off sc1"
                         : "=v"(hh) : "v"(hbase) : "memory");
            asm volatile("s_waitcnt vmcnt(0)" ::: "memory");
            __builtin_amdgcn_sched_barrier(0);
            const uint32_t o = (uint32_t)hh | (uint32_t)(hh >> 32);
            if ((o & TAG2) == 0u) break;   // parity-0 data present
        }
        float o[O_];
#pragma unroll
        for (int j = 0; j < O_; ++j) o[j] = 0.f;
#pragma unroll
        for (int e = 0; e < 4; ++e) {
            const float hv = f16_to_f((unsigned short)(hh >> (16 * e)));
            const float* wrow = W_ph + (size_t)(tid * 4 + e) * O_;
#pragma unroll
            for (int j = 0; j < O_; ++j) o[j] += hv * wrow[j];
        }
#pragma unroll
        for (int off = 32; off > 0; off >>= 1) {
#pragma unroll
            for (int j = 0; j < O_; ++j) o[j] += __shfl_down(o[j], off);
        }
        if (lane == 0) {
#pragma unroll
            for (int j = 0; j < O_; ++j) epi[w * 16 + j] = o[j];
        }
        __syncthreads();
        if (tid < O_) {
            float l = b_o[tid];
#pragma unroll
            for (int ww = 0; ww < 8; ++ww) l += epi[ww * 16 + tid];
            lgt[tid] = l;
        }
        __syncthreads();
        if (tid < O_) {
            float m = lgt[0];
#pragma unroll
            for (int j = 1; j < O_; ++j) m = fmaxf(m, lgt[j]);
            float ssum = 0.f;
#pragma unroll
            for (int j = 0; j < O_; ++j) ssum += expf(lgt[j] - m);
            out[(size_t)b * O_ + tid] = expf(lgt[tid] - m) / ssum;
        }
    }
}

extern "C" void kernel_launch(void* const* d_in, const int* in_sizes, int n_in,
                              void* d_out, int out_size, void* d_ws, size_t ws_size,
                              hipStream_t stream) {
    const float* x    = (const float*)d_in[0];
    const float* Whx  = (const float*)d_in[1];
    const float* Whh  = (const float*)d_in[2];
    const float* bh   = (const float*)d_in[3];
    const float* Wph  = (const float*)d_in[4];
    const float* bo   = (const float*)d_in[5];
    float* out = (float*)d_out;

    // ws: Wt (f16, 8.9MB) | h triple buffer (f16, 512KB x3)
    char* ws = (char*)d_ws;
    unsigned short* Wt = (unsigned short*)ws;
    unsigned short* h0 = Wt + (size_t)H_ * KK;
    unsigned short* h1 = h0 + (size_t)B_ * H_;
    unsigned short* h2 = h1 + (size_t)B_ * H_;

    hipLaunchKernelGGL(prep_init, dim3(512), dim3(256), 0, stream, h0, h1, h2);
    hipLaunchKernelGGL(prep_weights, dim3(68, 64), dim3(256), 0, stream, Whh, Whx, Wt);

    void* args[] = {
        (void*)&x, (void*)&Wt, (void*)&bh, (void*)&Wph, (void*)&bo,
        (void*)&h0, (void*)&h1, (void*)&h2, (void*)&out
    };
    hipLaunchCooperativeKernel((const void*)rnn_scan, dim3(NWG), dim3(NTHR), args, 0, stream);
}

// Round 13
// 2956.471 us; speedup vs baseline: 1.2032x; 1.2032x over previous
//
#include <hip/hip_runtime.h>
#include <stdint.h>

// VanillaRNN: B=128, T=512, I=128, H=2048, O=10
// R13: R8 (proven, 2141us) + speculative tagged consume with flag fallback.
//   Producer path = R8 exactly (hT -> 8B sc0sc1 stores -> vmcnt0 -> barrier
//   -> flag), values additionally carry bit14 step-parity tag (R11-proven).
//   Consumer: speculative 8-chunk burst + full-window tag validation;
//   hit -> consume, skip flag poll; miss -> R8's flag poll + reload (bounded,
//   live). 3-buffer rotation + prep-clear (R11-proven) for parity safety.

#define B_   128
#define T_   512
#define I_   128
#define H_   2048
#define O_   10
#define KK   2176
#define NWG  256
#define NTHR 512
#define TAG2 0x40004000u
#define MSK2 0xBFFFBFFFu

typedef __attribute__((ext_vector_type(8))) _Float16 f16x8;
typedef __attribute__((ext_vector_type(4))) float    f32x4;
typedef __attribute__((ext_vector_type(4))) int      i32x4;

__device__ __forceinline__ float f16_to_f(unsigned short u) {
    return (float)__builtin_bit_cast(_Float16, u);
}
__device__ __forceinline__ unsigned short f_to_f16(float f) {
    return __builtin_bit_cast(unsigned short, (_Float16)f);
}

// system-scope write-through stores (proven visibility)
__device__ __forceinline__ void st64cc(unsigned short* p, uint64_t v) {
    asm volatile("global_store_dwordx2 %0, %1, off sc0 sc1"
                 :: "v"((uint64_t)(uintptr_t)p), "v"(v) : "memory");
}
__device__ __forceinline__ void st32cc(uint32_t* p, uint32_t v) {
    asm volatile("global_store_dword %0, %1, off sc0 sc1"
                 :: "v"((uint64_t)(uintptr_t)p), "v"(v) : "memory");
}
__device__ __forceinline__ void stflag(unsigned int* p, uint32_t v) {
    asm volatile("global_store_dword %0, %1, off sc0 sc1"
                 :: "v"((uint64_t)(uintptr_t)p), "v"(v) : "memory");
}
__device__ __forceinline__ uint32_t ldflag(const unsigned int* p) {
    uint32_t v;
    asm volatile("global_load_dword %0, %1, off sc0 sc1"
                 : "=v"(v) : "v"((uint64_t)(uintptr_t)p) : "memory");
    asm volatile("s_waitcnt vmcnt(0)" ::: "memory");
    __builtin_amdgcn_sched_barrier(0);
    return v;
}

#define MFMA16(a, b, c) __builtin_amdgcn_mfma_f32_16x16x32_f16((a), (b), (c), 0, 0, 0)

// Clear flags + 3 h buffers each launch (replay safety). Tag-invalid patterns:
// h0/h1 (first expected parity 1 content) -> 0; h2 (first expected parity 0) -> TAG2.
__global__ void prep_init(unsigned int* flags,
                          unsigned short* h0, unsigned short* h1, unsigned short* h2) {
    const int i = blockIdx.x * blockDim.x + threadIdx.x;   // 0..131071 dwords
    if (i < 8192) flags[i] = 0u;
    st32cc((uint32_t*)h0 + i, 0u);
    st32cc((uint32_t*)h1 + i, 0u);
    st32cc((uint32_t*)h2 + i, TAG2);
}

// Transpose + f16 convert: Wt[n][k]; k<2048 -> W_hh, k>=2048 -> W_hx.
__global__ void prep_weights(const float* __restrict__ Whh, const float* __restrict__ Whx,
                             unsigned short* __restrict__ Wt) {
    __shared__ float tile[32][33];
    const int kt = blockIdx.x;
    const int nt = blockIdx.y;
    const int tx = threadIdx.x & 31;
    const int ty = threadIdx.x >> 5;
#pragma unroll
    for (int r = ty; r < 32; r += 8) {
        const int k = kt * 32 + r;
        const int n = nt * 32 + tx;
        tile[r][tx] = (k < H_) ? Whh[(size_t)k * H_ + n] : Whx[(size_t)(k - H_) * H_ + n];
    }
    __syncthreads();
#pragma unroll
    for (int r = ty; r < 32; r += 8) {
        const int n = nt * 32 + r;
        const int k = kt * 32 + tx;
        Wt[(size_t)n * KK + k] = f_to_f16(tile[tx][r]);
    }
}

__global__ __launch_bounds__(NTHR, 2) void rnn_scan(
    const float* __restrict__ x,              // [B][T][I] f32
    const unsigned short* __restrict__ Wt,    // [H][KK] f16
    const float* __restrict__ b_h,
    const float* __restrict__ W_ph,           // [H][O]
    const float* __restrict__ b_o,
    unsigned short* __restrict__ h0,          // s_t, t%3==0
    unsigned short* __restrict__ h1,          // t%3==1
    unsigned short* __restrict__ h2,          // t%3==2
    float* __restrict__ out,                  // [B][O]
    unsigned int* __restrict__ flags)
{
    const int tid  = threadIdx.x;
    const int wg   = blockIdx.x;
    const int w    = tid >> 6;        // wave 0..7 = k-eighth
    const int lane = tid & 63;
    const int l15  = lane & 15;
    const int l4   = lane >> 4;
    const int rb   = wg >> 5;         // row-group 0..7 (rows rb*16..+16)
    const int cb   = wg & 31;         // col block 0..31
    const int r0   = rb * 16;
    const int c0   = cb * 64;
    const int arow = r0 + l15;

    unsigned int* gslots = flags + 16 + (size_t)(rb * 32) * 16;  // group's 32 slots
    unsigned int* myslot = gslots + (size_t)cb * 16;
    // wave w's 4 producers: peers cb' = 4w .. 4w+3 (cols [cb'*64,+64))
    unsigned int* prodslot = gslots + (size_t)((w * 4 + (lane & 3)) * 16);

    __shared__ f32x4 red[8][4][64];          // 32 KB
    __shared__ unsigned short hT[16][68];    // tagged h staging
    __shared__ float epi[128];
    __shared__ float lgt[16];

    // ---- W panel into registers (f16, const over t) ----
    i32x4 wh[4][8];
    i32x4 wx[4];
#pragma unroll
    for (int n = 0; n < 4; ++n) {
        const size_t colbase = (size_t)(c0 + n * 16 + l15) * KK;
#pragma unroll
        for (int j = 0; j < 8; ++j)
            wh[n][j] = *(const i32x4*)(Wt + colbase + (size_t)(w * 256 + j * 32 + l4 * 8));
        if (w >= 4)
            wx[n] = *(const i32x4*)(Wt + colbase + (size_t)(2048 + (w - 4) * 32 + l4 * 8));
    }

    // reducer constants (tid < 256)
    const int rn   = tid >> 6;
    const int rL   = tid & 63;
    const int lcol = rn * 16 + (rL & 15);    // local col 0..63
    const int lr0  = (rL >> 4) * 4;          // local row 0,4,8,12
    const float rbias = b_h[c0 + lcol];
    const int slr = tid >> 4;                // store: local row 0..15
    const int scg = tid & 15;                // store: col group 0..15

    unsigned short* cur = h0;
    unsigned short* nxt = h1;
    unsigned short* old = h2;

    for (int t = 0; t < T_; ++t) {
        const int par = t & 1;               // expected tag parity of s_t

        f32x4 acc[4];
#pragma unroll
        for (int n = 0; n < 4; ++n) acc[n] = f32x4{0.f, 0.f, 0.f, 0.f};

        i32x4 hb[8];
        const uint64_t base64 = (uint64_t)(uintptr_t)(cur + (size_t)arow * H_ + (size_t)(w * 256 + l4 * 8));

#define ISSJ(jj, IMM) \
    asm volatile("global_load_dwordx4 %0, %1, off offset:" IMM " sc1" \
                 : "=v"(hb[jj]) : "v"(base64) : "memory")
#define ISSALL() do { \
    ISSJ(0, "0");   ISSJ(1, "64");  ISSJ(2, "128"); ISSJ(3, "192"); \
    ISSJ(4, "256"); ISSJ(5, "320"); ISSJ(6, "384"); ISSJ(7, "448"); } while (0)
#define WAITV(NSTR) do { \
    asm volatile("s_waitcnt vmcnt(" NSTR ")" ::: "memory"); \
    __builtin_amdgcn_sched_barrier(0); } while (0)
#define STRIPJ(jj) do { if (par) { \
    hb[jj][0] = (int)((uint32_t)hb[jj][0] & MSK2); \
    hb[jj][1] = (int)((uint32_t)hb[jj][1] & MSK2); \
    hb[jj][2] = (int)((uint32_t)hb[jj][2] & MSK2); \
    hb[jj][3] = (int)((uint32_t)hb[jj][3] & MSK2); } } while (0)
#define CONSJ(jj) do { \
    const f16x8 AH = __builtin_bit_cast(f16x8, hb[jj]); \
    acc[0] = MFMA16(AH, __builtin_bit_cast(f16x8, wh[0][jj]), acc[0]); \
    acc[1] = MFMA16(AH, __builtin_bit_cast(f16x8, wh[1][jj]), acc[1]); \
    acc[2] = MFMA16(AH, __builtin_bit_cast(f16x8, wh[2][jj]), acc[2]); \
    acc[3] = MFMA16(AH, __builtin_bit_cast(f16x8, wh[3][jj]), acc[3]); \
    } while (0)

        // ---- speculative burst issue (before anything else) ----
        if (t > 0) ISSALL();

        // ---- x contribution (waves 4..7) overlaps the load latency ----
        if (w >= 4) {
            const float* xp = x + ((size_t)arow * T_ + t) * I_ + (size_t)((w - 4) * 32 + l4 * 8);
            const f32x4 xa = *(const f32x4*)xp;
            const f32x4 xb = *(const f32x4*)(xp + 4);
            f16x8 xv;
#pragma unroll
            for (int jj = 0; jj < 8; ++jj)
                xv[jj] = (_Float16)((jj < 4) ? xa[jj] : xb[jj - 4]);
#pragma unroll
            for (int n = 0; n < 4; ++n)
                acc[n] = MFMA16(xv, __builtin_bit_cast(f16x8, wx[n]), acc[n]);
        }

        if (t > 0) {
            // ---- full-window tag validation of the speculative burst ----
            WAITV("0");
            uint32_t andv = 0xFFFFFFFFu, orv = 0u;
#pragma unroll
            for (int j = 0; j < 8; ++j) {
                const uint32_t d0 = (uint32_t)hb[j][0], d1 = (uint32_t)hb[j][1];
                const uint32_t d2 = (uint32_t)hb[j][2], d3 = (uint32_t)hb[j][3];
                andv &= (d0 & d1 & d2 & d3);
                orv  |= (d0 | d1 | d2 | d3);
            }
            const int ok = par ? ((andv & TAG2) == TAG2) : ((orv & TAG2) == 0u);
            if (__all(ok)) {
                // ---- HIT: consume directly, skip flag poll ----
#pragma unroll
                for (int j = 0; j < 8; ++j) { STRIPJ(j); CONSJ(j); }
            } else {
                // ---- MISS: R8's proven path (flag poll + reload) ----
                for (;;) {
                    uint32_t v = 0xFFFFFFFFu;
                    if ((lane & ~3) == 0) v = ldflag(prodslot);   // lanes 0..3
                    if (__all((int)(v >= (unsigned)t))) break;
                }
                ISSALL();
                WAITV("7"); STRIPJ(0); CONSJ(0);
                WAITV("6"); STRIPJ(1); CONSJ(1);
                WAITV("5"); STRIPJ(2); CONSJ(2);
                WAITV("4"); STRIPJ(3); CONSJ(3);
                WAITV("3"); STRIPJ(4); CONSJ(4);
                WAITV("2"); STRIPJ(5); CONSJ(5);
                WAITV("1"); STRIPJ(6); CONSJ(6);
                WAITV("0"); STRIPJ(7); CONSJ(7);
            }
        }
#undef ISSJ
#undef ISSALL
#undef WAITV
#undef STRIPJ
#undef CONSJ

        // ---- cross-wave k-reduce via LDS (R8 structure) ----
#pragma unroll
        for (int n = 0; n < 4; ++n) red[w][n][lane] = acc[n];
        __syncthreads();

        if (tid < 256) {
            f32x4 v = red[0][rn][rL];
#pragma unroll
            for (int p = 1; p < 8; ++p) v += red[p][rn][rL];
            const unsigned int tagbit = (unsigned int)((t + 1) & 1) << 14;
#pragma unroll
            for (int r = 0; r < 4; ++r)
                hT[lr0 + r][lcol] = (unsigned short)(f_to_f16(tanhf(v[r] + rbias)) | tagbit);
        }
        __syncthreads();

        // ---- coalesced tagged h store: 8B contiguous per thread ----
        if (tid < 256) {
            const uint64_t val = *(const uint64_t*)&hT[slr][scg * 4];
            st64cc(nxt + (size_t)(r0 + slr) * H_ + (size_t)(c0 + scg * 4), val);
        }
        asm volatile("s_waitcnt vmcnt(0)" ::: "memory");   // stores acked (R8)
        __syncthreads();                                    // all waves drained

        if (tid == 0) stflag(myslot, (unsigned)(t + 1));

        // rotate: (cur,nxt,old) <- (nxt, old, cur)
        unsigned short* tmp = cur;
        cur = nxt; nxt = old; old = tmp;
    }

    // ---- final group sync: all peers' h_T stores visible (R8 path) ----
    if (w == 0) {
        for (;;) {
            uint32_t v = 0xFFFFFFFFu;
            if (lane < 32) v = ldflag(gslots + (size_t)lane * 16);
            if (__all((int)(v >= (unsigned)T_))) break;
        }
    }
    __syncthreads();

    // ---- epilogue: row r0+cb handled by OWNER group rb (cb<16) ----
    // h_T = s_512 in buf 512%3=2 (h2), parity 0 => values untagged.
    if (cb < 16) {
        const int b = r0 + cb;
        const uint64_t hbase = (uint64_t)(uintptr_t)(h2 + (size_t)b * H_ + (size_t)tid * 4);
        uint64_t hh;
        asm volatile("global_load_dwordx2 %0, %1, off sc1"
                     : "=v"(hh) : "v"(hbase) : "memory");
        asm volatile("s_waitcnt vmcnt(0)" ::: "memory");
        __builtin_amdgcn_sched_barrier(0);
        float o[O_];
#pragma unroll
        for (int j = 0; j < O_; ++j) o[j] = 0.f;
#pragma unroll
        for (int e = 0; e < 4; ++e) {
            const float hv = f16_to_f((unsigned short)(hh >> (16 * e)));
            const float* wrow = W_ph + (size_t)(tid * 4 + e) * O_;
#pragma unroll
            for (int j = 0; j < O_; ++j) o[j] += hv * wrow[j];
        }
#pragma unroll
        for (int off = 32; off > 0; off >>= 1) {
#pragma unroll
            for (int j = 0; j < O_; ++j) o[j] += __shfl_down(o[j], off);
        }
        if (lane == 0) {
#pragma unroll
            for (int j = 0; j < O_; ++j) epi[w * 16 + j] = o[j];
        }
        __syncthreads();
        if (tid < O_) {
            float l = b_o[tid];
#pragma unroll
            for (int ww = 0; ww < 8; ++ww) l += epi[ww * 16 + tid];
            lgt[tid] = l;
        }
        __syncthreads();
        if (tid < O_) {
            float m = lgt[0];
#pragma unroll
            for (int j = 1; j < O_; ++j) m = fmaxf(m, lgt[j]);
            float ssum = 0.f;
#pragma unroll
            for (int j = 0; j < O_; ++j) ssum += expf(lgt[j] - m);
            out[(size_t)b * O_ + tid] = expf(lgt[tid] - m) / ssum;
        }
    }
}

extern "C" void kernel_launch(void* const* d_in, const int* in_sizes, int n_in,
                              void* d_out, int out_size, void* d_ws, size_t ws_size,
                              hipStream_t stream) {
    const float* x    = (const float*)d_in[0];
    const float* Whx  = (const float*)d_in[1];
    const float* Whh  = (const float*)d_in[2];
    const float* bh   = (const float*)d_in[3];
    const float* Wph  = (const float*)d_in[4];
    const float* bo   = (const float*)d_in[5];
    float* out = (float*)d_out;

    // ws: flags 32KB | Wt (f16, 8.9MB) | h triple buffer (f16, 512KB x3)
    char* ws = (char*)d_ws;
    unsigned int*   flags = (unsigned int*)ws;
    unsigned short* Wt    = (unsigned short*)(ws + 32768);
    unsigned short* h0    = Wt + (size_t)H_ * KK;
    unsigned short* h1    = h0 + (size_t)B_ * H_;
    unsigned short* h2    = h1 + (size_t)B_ * H_;

    hipLaunchKernelGGL(prep_init, dim3(512), dim3(256), 0, stream, flags, h0, h1, h2);
    hipLaunchKernelGGL(prep_weights, dim3(68, 64), dim3(256), 0, stream, Whh, Whx, Wt);

    void* args[] = {
        (void*)&x, (void*)&Wt, (void*)&bh, (void*)&Wph, (void*)&bo,
        (void*)&h0, (void*)&h1, (void*)&h2, (void*)&out, (void*)&flags
    };
    hipLaunchCooperativeKernel((const void*)rnn_scan, dim3(NWG), dim3(NTHR), args, 0, stream);
}